// Round 16
// baseline (314.135 us; speedup 1.0000x reference)
//
#include <hip/hip_runtime.h>
#include <cstdint>
#include <cstddef>

typedef _Float16 f16;
typedef _Float16 f16x8 __attribute__((ext_vector_type(8)));
typedef _Float16 f16x4 __attribute__((ext_vector_type(4)));
typedef float f32x16 __attribute__((ext_vector_type(16)));
typedef float f32x4 __attribute__((ext_vector_type(4)));

static constexpr int NPTS = 262144;

// Repacked weight offsets (in halfs). Each "tile" is 512 halfs = 64 lanes x 8.
// Fragment layout per tile (kt, ct): value = W[k][ch], k = kt*16 + (l>>5)*8 + j,
// ch = ct*32 + (l&31). Tiles ordered [segment][kt][ct], contiguous.
static constexpr int OFF_W0    = 0;        // 4 kt x 8 ct
static constexpr int OFF_W1    = 16384;    // 16 x 8
static constexpr int OFF_W2    = 81920;
static constexpr int OFF_W3    = 147456;
static constexpr int OFF_W4    = 212992;
static constexpr int OFF_W5    = 278528;   // w5b (16x8) then w5a (4x8), contiguous = 20 slices
static constexpr int OFF_W6    = 360448;
static constexpr int OFF_W7    = 425984;
static constexpr int OFF_FEAT  = 491520;
static constexpr int OFF_VIEWS = 557056;   // viewsA (16x4) then viewsB (2x4) = 18 slices of 2048
static constexpr int OFF_RGB   = 593920;   // 8 x 1

struct Seg { const float* src; int k0, rv, fo, ct, t0; };
struct RepParams { Seg seg[13]; f16* rep; };

__global__ void repack_kernel(RepParams P) {
  int tile = blockIdx.x;
  int s = 0;
  #pragma unroll
  for (int i = 1; i < 13; ++i)
    if (tile >= P.seg[i].t0) s = i;
  const Seg sg = P.seg[s];
  int local = tile - sg.t0;
  int kt = local / sg.ct;
  int ct = local - kt * sg.ct;
  int l = threadIdx.x;
  int ch = ct * 32 + (l & 31);
  int kbase = kt * 16 + ((l >> 5) << 3);
  f16x8 v;
  #pragma unroll
  for (int j = 0; j < 8; ++j) {
    int k = kbase + j;
    float val = 0.f;
    if (k < sg.rv && ch < sg.fo) val = sg.src[(size_t)(sg.k0 + k) * sg.fo + ch];
    v[j] = (f16)val;
  }
  *(f16x8*)(P.rep + (size_t)tile * 512 + (size_t)l * 8) = v;
}

struct MainParams {
  const float* x;
  const float* b[8];
  const float* feat_b;
  const float* alpha_w;
  const float* alpha_b;
  const float* views_b;
  const float* rgb_b;
  const f16* rep;
  float* out;
};

// Activation LDS: [pt<128][256ch] f16, 512 B rows, XOR swizzle.
__device__ __forceinline__ int act_off(int pt, int kbyte) {
  return pt * 512 + (kbyte ^ ((pt & 15) << 4));
}
// pos cache LDS: [pt<128][64ch] f16, 128 B rows, XOR swizzle.
__device__ __forceinline__ int pos_off(int pt, int kbyte) {
  return pt * 128 + (kbyte ^ ((pt & 7) << 4));
}

// 256-out layer; block = 4 waves (2ci x 2pi) x 128 pts, 2 blocks/CU ->
// 2 waves/SIMD. Wave tile = 128ch x 64pt (TRANSPOSED vs R12's 64x128 to
// halve the 4x-duplicated LDS B-read traffic: per-CU LDS drops 75% -> 37%
// of the MFMA window; A-frags double but same-ci waves read identical A ->
// L1 dedup, 8 KB/kt working set is L1-resident). acc[c][p] = 4x2x16 = 128
// f32 in AGPRs. Budget discipline (R13 lesson): A depth-2 (64 VGPR) +
// B depth-2 (32 VGPR) + misc ~ 120 VGPR + 128 AGPR < 256. setprio (T5).
template<int KTA, bool POSB, bool RELU>
__device__ __forceinline__ void layer_std(
    const f16* repL, const float* bias,
    f16* act, const f16* posb, int lane, int ci, int pi)
{
  constexpr int NT = KTA + (POSB ? 4 : 0);
  const int l31 = lane & 31;
  const int ln5 = lane >> 5;
  const int chb = ci * 128;
  const int ptb = pi * 64;

  f32x16 acc[4][2];
  #pragma unroll
  for (int c = 0; c < 4; ++c) {
    #pragma unroll
    for (int g = 0; g < 4; ++g) {
      f32x4 bv = *(const f32x4*)(bias + chb + c * 32 + g * 8 + (ln5 << 2));
      #pragma unroll
      for (int q = 0; q < 4; ++q) {
        acc[c][0][g * 4 + q] = bv[q];
        acc[c][1][g * 4 + q] = bv[q];
      }
    }
  }

  auto lda = [&](int kt, int c) -> f16x8 {
    return *(const f16x8*)(repL + (size_t)(kt * 8 + ci * 4 + c) * 512 + (size_t)lane * 8);
  };
  auto ldb = [&](int kt, int p) -> f16x8 {
    if (kt < KTA)
      return *(const f16x8*)((const char*)act + act_off(ptb + p * 32 + l31, (kt * 16 + ln5 * 8) * 2));
    else
      return *(const f16x8*)((const char*)posb + pos_off(ptb + p * 32 + l31, ((kt - KTA) * 16 + ln5 * 8) * 2));
  };

  f16x8 A[2][4], B[2][2];
  #pragma unroll
  for (int c = 0; c < 4; ++c) A[0][c] = lda(0, c);

  __syncthreads();  // prev epilogue writes (and prologue posb fill) visible

  #pragma unroll
  for (int p = 0; p < 2; ++p) B[0][p] = ldb(0, p);

  #pragma unroll
  for (int kt = 0; kt < NT; ++kt) {
    if (kt + 1 < NT) {
      #pragma unroll
      for (int c = 0; c < 4; ++c) A[(kt + 1) & 1][c] = lda(kt + 1, c);
      #pragma unroll
      for (int p = 0; p < 2; ++p) B[(kt + 1) & 1][p] = ldb(kt + 1, p);
    }
    __builtin_amdgcn_s_setprio(1);
    #pragma unroll
    for (int c = 0; c < 4; ++c)
      #pragma unroll
      for (int p = 0; p < 2; ++p)
        acc[c][p] = __builtin_amdgcn_mfma_f32_32x32x16_f16(A[kt & 1][c], B[kt & 1][p], acc[c][p], 0, 0, 0);
    __builtin_amdgcn_s_setprio(0);
  }

  __syncthreads();  // all B reads done -> safe to overwrite act in place

  // Epilogue: C row = (r&3) + 8*(r>>2) + 4*(l>>5), col = l&31 (pt).
  #pragma unroll
  for (int c = 0; c < 4; ++c) {
    #pragma unroll
    for (int p = 0; p < 2; ++p) {
      int pt = ptb + p * 32 + l31;
      #pragma unroll
      for (int g = 0; g < 4; ++g) {
        f16x4 h;
        #pragma unroll
        for (int q = 0; q < 4; ++q) {
          float v = acc[c][p][g * 4 + q];
          if (RELU) v = fmaxf(v, 0.f);
          h[q] = (f16)v;
        }
        int ch = chb + c * 32 + g * 8 + (ln5 << 2);
        *(f16x4*)((char*)act + act_off(pt, ch * 2)) = h;
      }
    }
  }
}

// Views layer: in = feature(256 from act) + views(27 gathered from x), out=128.
// Wave (ci,pi) -> ch [64ci, 64ci+64) x pts [64pi, 64pi+64). acc[2][2]=64 f32.
__device__ __forceinline__ void layer_views(
    const f16* repL, const float* bias, f16* act,
    const float* xrow0, int lane, int ci, int pi)
{
  const int l31 = lane & 31;
  const int ln5 = lane >> 5;
  const int chb = ci * 64;
  const int ptb = pi * 64;

  f32x16 acc[2][2];
  #pragma unroll
  for (int c = 0; c < 2; ++c) {
    #pragma unroll
    for (int g = 0; g < 4; ++g) {
      f32x4 bv = *(const f32x4*)(bias + chb + c * 32 + g * 8 + (ln5 << 2));
      #pragma unroll
      for (int q = 0; q < 4; ++q) {
        acc[c][0][g * 4 + q] = bv[q];
        acc[c][1][g * 4 + q] = bv[q];
      }
    }
  }

  // Views part first (gathered from x; no act dependency -> before sync).
  #pragma unroll
  for (int j = 0; j < 2; ++j) {
    f16x8 vf[2];
    #pragma unroll
    for (int p = 0; p < 2; ++p) {
      const float* row = xrow0 + (size_t)(ptb + p * 32 + l31) * 90;
      #pragma unroll
      for (int jj = 0; jj < 8; ++jj) {
        int c = j * 16 + ln5 * 8 + jj;
        vf[p][jj] = (f16)((c < 27) ? row[63 + c] : 0.f);
      }
    }
    #pragma unroll
    for (int c = 0; c < 2; ++c) {
      f16x8 a = *(const f16x8*)(repL + (size_t)((16 + j) * 4 + ci * 2 + c) * 512 + (size_t)lane * 8);
      #pragma unroll
      for (int p = 0; p < 2; ++p)
        acc[c][p] = __builtin_amdgcn_mfma_f32_32x32x16_f16(a, vf[p], acc[c][p], 0, 0, 0);
    }
  }

  auto lda = [&](int kt, int c) -> f16x8 {
    return *(const f16x8*)(repL + (size_t)(kt * 4 + ci * 2 + c) * 512 + (size_t)lane * 8);
  };
  auto ldb = [&](int kt, int p) -> f16x8 {
    return *(const f16x8*)((const char*)act + act_off(ptb + p * 32 + l31, (kt * 16 + ln5 * 8) * 2));
  };

  f16x8 A[2][2], B[2][2];
  #pragma unroll
  for (int c = 0; c < 2; ++c) A[0][c] = lda(0, c);

  __syncthreads();

  #pragma unroll
  for (int p = 0; p < 2; ++p) B[0][p] = ldb(0, p);

  #pragma unroll
  for (int kt = 0; kt < 16; ++kt) {
    if (kt + 1 < 16) {
      #pragma unroll
      for (int c = 0; c < 2; ++c) A[(kt + 1) & 1][c] = lda(kt + 1, c);
      #pragma unroll
      for (int p = 0; p < 2; ++p) B[(kt + 1) & 1][p] = ldb(kt + 1, p);
    }
    __builtin_amdgcn_s_setprio(1);
    #pragma unroll
    for (int c = 0; c < 2; ++c)
      #pragma unroll
      for (int p = 0; p < 2; ++p)
        acc[c][p] = __builtin_amdgcn_mfma_f32_32x32x16_f16(A[kt & 1][c], B[kt & 1][p], acc[c][p], 0, 0, 0);
    __builtin_amdgcn_s_setprio(0);
  }

  __syncthreads();

  #pragma unroll
  for (int c = 0; c < 2; ++c) {
    #pragma unroll
    for (int p = 0; p < 2; ++p) {
      int pt = ptb + p * 32 + l31;
      #pragma unroll
      for (int g = 0; g < 4; ++g) {
        f16x4 h;
        #pragma unroll
        for (int q = 0; q < 4; ++q) {
          float v = fmaxf(acc[c][p][g * 4 + q], 0.f);
          h[q] = (f16)v;
        }
        int ch = chb + c * 32 + g * 8 + (ln5 << 2);
        *(f16x4*)((char*)act + act_off(pt, ch * 2)) = h;
      }
    }
  }
}

// alpha = y . alpha_w + alpha_b. 2 threads per point (128 pts, 256 threads),
// intra-wave shfl reduce; result into alds (reused posb memory).
__device__ __forceinline__ void alpha_pass(const f16* act, const float* aw,
                                           const float* ab, float* alds, int tid)
{
  __syncthreads();
  int pt = tid >> 1;
  int h = tid & 1;
  float s = 0.f;
  #pragma unroll
  for (int i = 0; i < 16; ++i) {
    int k0 = h * 128 + i * 8;
    f16x8 v = *(const f16x8*)((const char*)act + act_off(pt, k0 * 2));
    f32x4 wa = *(const f32x4*)(aw + k0);
    f32x4 wb = *(const f32x4*)(aw + k0 + 4);
    #pragma unroll
    for (int q = 0; q < 4; ++q) {
      s += (float)v[q] * wa[q];
      s += (float)v[q + 4] * wb[q];
    }
  }
  s += __shfl_xor(s, 1);
  if (h == 0) alds[pt] = s + ab[0];
}

// rgb (128 -> 3 via one padded 32-ch MFMA tile per wave): pt-tile = w.
// A fully preloaded (8 frags), B depth-2 pipelined.
__device__ __forceinline__ void layer_rgb_store(
    const f16* repL, f16* act, const float* alds,
    const float* rgb_b, float* out, int pt0, int lane, int w)
{
  f16x8 A[8];
  #pragma unroll
  for (int kt = 0; kt < 8; ++kt)
    A[kt] = *(const f16x8*)(repL + (size_t)kt * 512 + (size_t)lane * 8);

  __syncthreads();

  auto ldb = [&](int kt) -> f16x8 {
    return *(const f16x8*)((const char*)act + act_off(w * 32 + (lane & 31), (kt * 16 + (lane >> 5) * 8) * 2));
  };

  f32x16 acc = {};
  f16x8 B[2];
  B[0] = ldb(0);
  #pragma unroll
  for (int kt = 0; kt < 8; ++kt) {
    if (kt + 1 < 8) B[(kt + 1) & 1] = ldb(kt + 1);
    acc = __builtin_amdgcn_mfma_f32_32x32x16_f16(A[kt], B[kt & 1], acc, 0, 0, 0);
  }

  if (lane < 32) {
    int pt = w * 32 + lane;
    float4 o;
    o.x = acc[0] + rgb_b[0];
    o.y = acc[1] + rgb_b[1];
    o.z = acc[2] + rgb_b[2];
    o.w = alds[pt];
    *(float4*)(out + (size_t)(pt0 + pt) * 4) = o;
  }
}

__global__ __launch_bounds__(256, 2) void nerf_main(MainParams P) {
  __shared__ __align__(16) f16 act[32768];   // 64 KB: [128 pt][256 k], swizzled
  __shared__ __align__(16) f16 posb[8192];   // 16 KB: [128 pt][64 k] pos cache

  const int tid = threadIdx.x;
  const int lane = tid & 63;
  const int w = tid >> 6;                // 4 waves
  const int ci = w >> 1;                 // ch-half  (128 ch per ci)
  const int pi = w & 1;                  // pt-half  (64 pt per pi)
  const int pt0 = blockIdx.x * 128;
  const float* xrow0 = P.x + (size_t)pt0 * 90;

  // Prologue: gather pos (63 ch, pad to 64) into posb ONCE, B-frag layout.
  // 256 threads: pt = tid&127, col-half q = tid>>7 (32 ch each).
  // Rows are 8-byte aligned (90 floats = 360 B stride) -> float2 loads.
  {
    int pt = tid & 127;
    int q = tid >> 7;
    const float* rowq = xrow0 + (size_t)pt * 90 + q * 32;
    #pragma unroll
    for (int h = 0; h < 4; ++h) {
      f16x8 v;
      #pragma unroll
      for (int m = 0; m < 4; ++m) {
        float2 f = *(const float2*)(rowq + h * 8 + m * 2);
        v[m * 2]     = (f16)f.x;
        v[m * 2 + 1] = (f16)f.y;
      }
      if (q == 1 && h == 3) v[7] = (f16)0.f;   // pad k=63 -> 0
      *(f16x8*)((char*)posb + pos_off(pt, (q * 32 + h * 8) * 2)) = v;
    }
  }

  layer_std<0, true, true>(P.rep + OFF_W0, P.b[0], act, posb, lane, ci, pi);
  layer_std<16, false, true>(P.rep + OFF_W1, P.b[1], act, posb, lane, ci, pi);
  layer_std<16, false, true>(P.rep + OFF_W2, P.b[2], act, posb, lane, ci, pi);
  layer_std<16, false, true>(P.rep + OFF_W3, P.b[3], act, posb, lane, ci, pi);
  layer_std<16, false, true>(P.rep + OFF_W4, P.b[4], act, posb, lane, ci, pi);
  layer_std<16, true, true>(P.rep + OFF_W5, P.b[5], act, posb, lane, ci, pi);
  layer_std<16, false, true>(P.rep + OFF_W6, P.b[6], act, posb, lane, ci, pi);
  layer_std<16, false, true>(P.rep + OFF_W7, P.b[7], act, posb, lane, ci, pi);

  // posb is dead after L5 -> reuse as alpha scratch.
  float* alds = (float*)posb;
  alpha_pass(act, P.alpha_w, P.alpha_b, alds, tid);

  layer_std<16, false, false>(P.rep + OFF_FEAT, P.feat_b, act, posb, lane, ci, pi);

  layer_views(P.rep + OFF_VIEWS, P.views_b, act, xrow0, lane, ci, pi);

  layer_rgb_store(P.rep + OFF_RGB, act, alds, P.rgb_b, P.out, pt0, lane, w);

  // Second tuple output: zeros (N, 3) -> 384 floats per 128-pt block
  float* out2 = P.out + (size_t)NPTS * 4;
  if (tid < 96) {
    *(float4*)(out2 + (size_t)blockIdx.x * 384 + (size_t)tid * 4) =
        make_float4(0.f, 0.f, 0.f, 0.f);
  }
}

extern "C" void kernel_launch(void* const* d_in, const int* in_sizes, int n_in,
                              void* d_out, int out_size, void* d_ws, size_t ws_size,
                              hipStream_t stream) {
  (void)in_sizes; (void)n_in; (void)out_size; (void)ws_size;

  RepParams rp;
  rp.seg[0]  = { (const float*)d_in[1],    0,  63, 256, 8,    0 }; // w0 (pad K 63->64)
  rp.seg[1]  = { (const float*)d_in[3],    0, 256, 256, 8,   32 }; // w1
  rp.seg[2]  = { (const float*)d_in[5],    0, 256, 256, 8,  160 }; // w2
  rp.seg[3]  = { (const float*)d_in[7],    0, 256, 256, 8,  288 }; // w3
  rp.seg[4]  = { (const float*)d_in[9],    0, 256, 256, 8,  416 }; // w4
  rp.seg[5]  = { (const float*)d_in[11],  63, 256, 256, 8,  544 }; // w5 y-part (rows 63..318)
  rp.seg[6]  = { (const float*)d_in[11],   0,  63, 256, 8,  672 }; // w5 pos-part (rows 0..62)
  rp.seg[7]  = { (const float*)d_in[13],   0, 256, 256, 8,  704 }; // w6
  rp.seg[8]  = { (const float*)d_in[15],   0, 256, 256, 8,  832 }; // w7
  rp.seg[9]  = { (const float*)d_in[17],   0, 256, 256, 8,  960 }; // feat_w
  rp.seg[10] = { (const float*)d_in[21],   0, 256, 128, 4, 1088 }; // views_w feature-part
  rp.seg[11] = { (const float*)d_in[21], 256,  27, 128, 4, 1152 }; // views_w views-part
  rp.seg[12] = { (const float*)d_in[23],   0, 128,   3, 1, 1160 }; // rgb_w (pad 3->32 ch)
  rp.rep = (f16*)d_ws;
  repack_kernel<<<1168, 64, 0, stream>>>(rp);

  MainParams mp;
  mp.x = (const float*)d_in[0];
  for (int i = 0; i < 8; ++i) mp.b[i] = (const float*)d_in[2 + 2 * i];
  mp.feat_b  = (const float*)d_in[18];
  mp.alpha_w = (const float*)d_in[19];
  mp.alpha_b = (const float*)d_in[20];
  mp.views_b = (const float*)d_in[22];
  mp.rgb_b   = (const float*)d_in[24];
  mp.rep = (const f16*)d_ws;
  mp.out = (float*)d_out;
  nerf_main<<<2048, 256, 0, stream>>>(mp);
}

// Round 17
// 297.858 us; speedup vs baseline: 1.0546x; 1.0546x over previous
//
#include <hip/hip_runtime.h>
#include <cstdint>
#include <cstddef>

typedef _Float16 f16;
typedef _Float16 f16x8 __attribute__((ext_vector_type(8)));
typedef _Float16 f16x4 __attribute__((ext_vector_type(4)));
typedef float f32x16 __attribute__((ext_vector_type(16)));
typedef float f32x4 __attribute__((ext_vector_type(4)));

static constexpr int NPTS = 262144;

// Repacked weight offsets (in halfs). Each "tile" is 512 halfs = 64 lanes x 8.
// Fragment layout per tile (kt, ct): value = W[k][ch], k = kt*16 + (l>>5)*8 + j,
// ch = ct*32 + (l&31). Tiles ordered [segment][kt][ct], contiguous.
static constexpr int OFF_W0    = 0;        // 4 kt x 8 ct
static constexpr int OFF_W1    = 16384;    // 16 x 8
static constexpr int OFF_W2    = 81920;
static constexpr int OFF_W3    = 147456;
static constexpr int OFF_W4    = 212992;
static constexpr int OFF_W5    = 278528;   // w5b (16x8) then w5a (4x8), contiguous = 20 slices
static constexpr int OFF_W6    = 360448;
static constexpr int OFF_W7    = 425984;
static constexpr int OFF_FEAT  = 491520;
static constexpr int OFF_VIEWS = 557056;   // viewsA (16x4) then viewsB (2x4) = 18 slices of 2048
static constexpr int OFF_RGB   = 593920;   // 8 x 1

struct Seg { const float* src; int k0, rv, fo, ct, t0; };
struct RepParams { Seg seg[13]; f16* rep; };

__global__ void repack_kernel(RepParams P) {
  int tile = blockIdx.x;
  int s = 0;
  #pragma unroll
  for (int i = 1; i < 13; ++i)
    if (tile >= P.seg[i].t0) s = i;
  const Seg sg = P.seg[s];
  int local = tile - sg.t0;
  int kt = local / sg.ct;
  int ct = local - kt * sg.ct;
  int l = threadIdx.x;
  int ch = ct * 32 + (l & 31);
  int kbase = kt * 16 + ((l >> 5) << 3);
  f16x8 v;
  #pragma unroll
  for (int j = 0; j < 8; ++j) {
    int k = kbase + j;
    float val = 0.f;
    if (k < sg.rv && ch < sg.fo) val = sg.src[(size_t)(sg.k0 + k) * sg.fo + ch];
    v[j] = (f16)val;
  }
  *(f16x8*)(P.rep + (size_t)tile * 512 + (size_t)l * 8) = v;
}

struct MainParams {
  const float* x;
  const float* b[8];
  const float* feat_b;
  const float* alpha_w;
  const float* alpha_b;
  const float* views_b;
  const float* rgb_b;
  const f16* rep;
  float* out;
};

// Activation LDS: [pt<128][256ch] f16, 512 B rows, XOR swizzle.
__device__ __forceinline__ int act_off(int pt, int kbyte) {
  return pt * 512 + (kbyte ^ ((pt & 15) << 4));
}
// pos cache LDS: [pt<128][64ch] f16, 128 B rows, XOR swizzle.
__device__ __forceinline__ int pos_off(int pt, int kbyte) {
  return pt * 128 + (kbyte ^ ((pt & 7) << 4));
}

// 256-out layer; block = 4 waves x 128 pts, 2 blocks/CU -> 2 waves/SIMD
// (one wave from each co-resident block per SIMD; blocks are anti-phased by
// the bit-8 s_sleep stagger in main so one block's K-loop covers the other's
// boundary stalls). Wave w: ch [64w, 64w+64) x all 128 pts; acc[c][p] = 128
// f32 (AGPRs). SOFTWARE-PIPELINED: A depth-3 rotate (2 kt ahead), B depth-2
// (1 kt ahead). setprio(1) around the MFMA cluster (T5). Do NOT add register
// load here (R13: spills) and do NOT rebalance the tile (R16: A-feed hits
// the L1 64 B/cyc ceiling at CH=128/wave).
template<int KTA, bool POSB, bool RELU>
__device__ __forceinline__ void layer_std(
    const f16* repL, const float* bias,
    f16* act, const f16* posb, int lane, int w)
{
  constexpr int NT = KTA + (POSB ? 4 : 0);
  const int l31 = lane & 31;
  const int ln5 = lane >> 5;
  const int chb = w * 64;

  f32x16 acc[2][4];
  #pragma unroll
  for (int c = 0; c < 2; ++c) {
    #pragma unroll
    for (int g = 0; g < 4; ++g) {
      f32x4 bv = *(const f32x4*)(bias + chb + c * 32 + g * 8 + (ln5 << 2));
      #pragma unroll
      for (int p = 0; p < 4; ++p) {
        #pragma unroll
        for (int q = 0; q < 4; ++q) acc[c][p][g * 4 + q] = bv[q];
      }
    }
  }

  auto lda = [&](int kt, int c) -> f16x8 {
    return *(const f16x8*)(repL + (size_t)(kt * 8 + 2 * w + c) * 512 + (size_t)lane * 8);
  };
  auto ldb = [&](int kt, int p) -> f16x8 {
    if (kt < KTA)
      return *(const f16x8*)((const char*)act + act_off(p * 32 + l31, (kt * 16 + ln5 * 8) * 2));
    else
      return *(const f16x8*)((const char*)posb + pos_off(p * 32 + l31, ((kt - KTA) * 16 + ln5 * 8) * 2));
  };

  f16x8 A[3][2], B[2][4];
  #pragma unroll
  for (int c = 0; c < 2; ++c) {
    A[0][c] = lda(0, c);
    A[1][c] = lda(1, c);   // NT >= 4 always
  }

  __syncthreads();  // prev epilogue writes (and prologue posb fill) visible

  #pragma unroll
  for (int p = 0; p < 4; ++p) B[0][p] = ldb(0, p);

  #pragma unroll
  for (int kt = 0; kt < NT; ++kt) {
    if (kt + 2 < NT) {
      #pragma unroll
      for (int c = 0; c < 2; ++c) A[(kt + 2) % 3][c] = lda(kt + 2, c);
    }
    if (kt + 1 < NT) {
      #pragma unroll
      for (int p = 0; p < 4; ++p) B[(kt + 1) & 1][p] = ldb(kt + 1, p);
    }
    __builtin_amdgcn_s_setprio(1);
    #pragma unroll
    for (int c = 0; c < 2; ++c)
      #pragma unroll
      for (int p = 0; p < 4; ++p)
        acc[c][p] = __builtin_amdgcn_mfma_f32_32x32x16_f16(A[kt % 3][c], B[kt & 1][p], acc[c][p], 0, 0, 0);
    __builtin_amdgcn_s_setprio(0);
  }

  __syncthreads();  // all B reads done -> safe to overwrite act in place

  // Epilogue: C row = (r&3) + 8*(r>>2) + 4*(l>>5), col = l&31 (pt).
  #pragma unroll
  for (int c = 0; c < 2; ++c) {
    #pragma unroll
    for (int p = 0; p < 4; ++p) {
      int pt = p * 32 + l31;
      #pragma unroll
      for (int g = 0; g < 4; ++g) {
        f16x4 h;
        #pragma unroll
        for (int q = 0; q < 4; ++q) {
          float v = acc[c][p][g * 4 + q];
          if (RELU) v = fmaxf(v, 0.f);
          h[q] = (f16)v;
        }
        int ch = chb + c * 32 + g * 8 + (ln5 << 2);
        *(f16x4*)((char*)act + act_off(pt, ch * 2)) = h;
      }
    }
  }
}

// Views layer: in = feature(256 from act) + views(27 gathered from x), out=128.
// Wave w -> ch [32w, 32w+32) x all 128 pts. Same pipelined K-loop.
__device__ __forceinline__ void layer_views(
    const f16* repL, const float* bias, f16* act,
    const float* xrow0, int lane, int w)
{
  const int l31 = lane & 31;
  const int ln5 = lane >> 5;
  const int chb = w * 32;

  f32x16 acc[4];
  #pragma unroll
  for (int g = 0; g < 4; ++g) {
    f32x4 bv = *(const f32x4*)(bias + chb + g * 8 + (ln5 << 2));
    #pragma unroll
    for (int p = 0; p < 4; ++p)
      #pragma unroll
      for (int q = 0; q < 4; ++q) acc[p][g * 4 + q] = bv[q];
  }

  // Views part first (gathered from x; no act dependency -> before sync).
  #pragma unroll
  for (int j = 0; j < 2; ++j) {
    f16x8 a = *(const f16x8*)(repL + (size_t)((16 + j) * 4 + w) * 512 + (size_t)lane * 8);
    #pragma unroll
    for (int p = 0; p < 4; ++p) {
      f16x8 vf;
      const float* row = xrow0 + (size_t)(p * 32 + l31) * 90;
      #pragma unroll
      for (int jj = 0; jj < 8; ++jj) {
        int c = j * 16 + ln5 * 8 + jj;
        vf[jj] = (f16)((c < 27) ? row[63 + c] : 0.f);
      }
      acc[p] = __builtin_amdgcn_mfma_f32_32x32x16_f16(a, vf, acc[p], 0, 0, 0);
    }
  }

  auto lda = [&](int kt) -> f16x8 {
    return *(const f16x8*)(repL + (size_t)(kt * 4 + w) * 512 + (size_t)lane * 8);
  };
  auto ldb = [&](int kt, int p) -> f16x8 {
    return *(const f16x8*)((const char*)act + act_off(p * 32 + l31, (kt * 16 + ln5 * 8) * 2));
  };

  f16x8 A[3], B[2][4];
  A[0] = lda(0);
  A[1] = lda(1);

  __syncthreads();

  #pragma unroll
  for (int p = 0; p < 4; ++p) B[0][p] = ldb(0, p);

  #pragma unroll
  for (int kt = 0; kt < 16; ++kt) {
    if (kt + 2 < 16) A[(kt + 2) % 3] = lda(kt + 2);
    if (kt + 1 < 16) {
      #pragma unroll
      for (int p = 0; p < 4; ++p) B[(kt + 1) & 1][p] = ldb(kt + 1, p);
    }
    __builtin_amdgcn_s_setprio(1);
    #pragma unroll
    for (int p = 0; p < 4; ++p)
      acc[p] = __builtin_amdgcn_mfma_f32_32x32x16_f16(A[kt % 3], B[kt & 1][p], acc[p], 0, 0, 0);
    __builtin_amdgcn_s_setprio(0);
  }

  __syncthreads();

  #pragma unroll
  for (int p = 0; p < 4; ++p) {
    int pt = p * 32 + l31;
    #pragma unroll
    for (int g = 0; g < 4; ++g) {
      f16x4 h;
      #pragma unroll
      for (int q = 0; q < 4; ++q) {
        float v = fmaxf(acc[p][g * 4 + q], 0.f);
        h[q] = (f16)v;
      }
      int ch = chb + g * 8 + (ln5 << 2);
      *(f16x4*)((char*)act + act_off(pt, ch * 2)) = h;
    }
  }
}

// alpha = y . alpha_w + alpha_b. 2 threads per point (128 pts, 256 threads),
// intra-wave shfl reduce; result into alds (reused posb memory).
__device__ __forceinline__ void alpha_pass(const f16* act, const float* aw,
                                           const float* ab, float* alds, int tid)
{
  __syncthreads();
  int pt = tid >> 1;
  int h = tid & 1;
  float s = 0.f;
  #pragma unroll
  for (int i = 0; i < 16; ++i) {
    int k0 = h * 128 + i * 8;
    f16x8 v = *(const f16x8*)((const char*)act + act_off(pt, k0 * 2));
    f32x4 wa = *(const f32x4*)(aw + k0);
    f32x4 wb = *(const f32x4*)(aw + k0 + 4);
    #pragma unroll
    for (int q = 0; q < 4; ++q) {
      s += (float)v[q] * wa[q];
      s += (float)v[q + 4] * wb[q];
    }
  }
  s += __shfl_xor(s, 1);
  if (h == 0) alds[pt] = s + ab[0];
}

// rgb (128 -> 3 via one padded 32-ch MFMA tile per wave): pt-tile = w.
// A fully preloaded (8 frags), B depth-2 pipelined.
__device__ __forceinline__ void layer_rgb_store(
    const f16* repL, f16* act, const float* alds,
    const float* rgb_b, float* out, int pt0, int lane, int w)
{
  f16x8 A[8];
  #pragma unroll
  for (int kt = 0; kt < 8; ++kt)
    A[kt] = *(const f16x8*)(repL + (size_t)kt * 512 + (size_t)lane * 8);

  __syncthreads();

  auto ldb = [&](int kt) -> f16x8 {
    return *(const f16x8*)((const char*)act + act_off(w * 32 + (lane & 31), (kt * 16 + (lane >> 5) * 8) * 2));
  };

  f32x16 acc = {};
  f16x8 B[2];
  B[0] = ldb(0);
  #pragma unroll
  for (int kt = 0; kt < 8; ++kt) {
    if (kt + 1 < 8) B[(kt + 1) & 1] = ldb(kt + 1);
    acc = __builtin_amdgcn_mfma_f32_32x32x16_f16(A[kt], B[kt & 1], acc, 0, 0, 0);
  }

  if (lane < 32) {
    int pt = w * 32 + lane;
    float4 o;
    o.x = acc[0] + rgb_b[0];
    o.y = acc[1] + rgb_b[1];
    o.z = acc[2] + rgb_b[2];
    o.w = alds[pt];
    *(float4*)(out + (size_t)(pt0 + pt) * 4) = o;
  }
}

__global__ __launch_bounds__(256, 2) void nerf_main(MainParams P) {
  __shared__ __align__(16) f16 act[32768];   // 64 KB: [128 pt][256 k], swizzled
  __shared__ __align__(16) f16 posb[8192];   // 16 KB: [128 pt][64 k] pos cache

  const int tid = threadIdx.x;
  const int lane = tid & 63;
  const int w = tid >> 6;                // 4 waves
  const int pt0 = blockIdx.x * 128;
  const float* xrow0 = P.x + (size_t)pt0 * 90;

  // ANTI-PHASE STAGGER, take 2 (R15 used bit 0 -- WRONG BIT). With XCD
  // round-robin dispatch (b%8 -> XCD, then b/8 round-robins CUs), the two
  // co-resident blocks on a CU are b and b+256: same bit 0, DIFFERENT BIT 8.
  // Subsequent generations in a slot differ by +512 (bit 9), so a slot's
  // bit-8 parity -- and hence the phase offset -- persists for the whole
  // kernel. Sleep ~8.1k cyc ~ half the ~16k-cyc layer wall to anti-phase the
  // two slots: one block's K-loop MFMAs fill the other's boundary stalls.
  if ((blockIdx.x >> 8) & 1) {
    __builtin_amdgcn_s_sleep(127);
  }

  // Prologue: gather pos (63 ch, pad to 64) into posb ONCE, B-frag layout.
  // 256 threads: pt = tid&127, col-half q = tid>>7 (32 ch each).
  // Rows are 8-byte aligned (90 floats = 360 B stride) -> float2 loads.
  {
    int pt = tid & 127;
    int q = tid >> 7;
    const float* rowq = xrow0 + (size_t)pt * 90 + q * 32;
    #pragma unroll
    for (int h = 0; h < 4; ++h) {
      f16x8 v;
      #pragma unroll
      for (int m = 0; m < 4; ++m) {
        float2 f = *(const float2*)(rowq + h * 8 + m * 2);
        v[m * 2]     = (f16)f.x;
        v[m * 2 + 1] = (f16)f.y;
      }
      if (q == 1 && h == 3) v[7] = (f16)0.f;   // pad k=63 -> 0
      *(f16x8*)((char*)posb + pos_off(pt, (q * 32 + h * 8) * 2)) = v;
    }
  }

  layer_std<0, true, true>(P.rep + OFF_W0, P.b[0], act, posb, lane, w);
  layer_std<16, false, true>(P.rep + OFF_W1, P.b[1], act, posb, lane, w);
  layer_std<16, false, true>(P.rep + OFF_W2, P.b[2], act, posb, lane, w);
  layer_std<16, false, true>(P.rep + OFF_W3, P.b[3], act, posb, lane, w);
  layer_std<16, false, true>(P.rep + OFF_W4, P.b[4], act, posb, lane, w);
  layer_std<16, true, true>(P.rep + OFF_W5, P.b[5], act, posb, lane, w);
  layer_std<16, false, true>(P.rep + OFF_W6, P.b[6], act, posb, lane, w);
  layer_std<16, false, true>(P.rep + OFF_W7, P.b[7], act, posb, lane, w);

  // posb is dead after L5 -> reuse as alpha scratch.
  float* alds = (float*)posb;
  alpha_pass(act, P.alpha_w, P.alpha_b, alds, tid);

  layer_std<16, false, false>(P.rep + OFF_FEAT, P.feat_b, act, posb, lane, w);

  layer_views(P.rep + OFF_VIEWS, P.views_b, act, xrow0, lane, w);

  layer_rgb_store(P.rep + OFF_RGB, act, alds, P.rgb_b, P.out, pt0, lane, w);

  // Second tuple output: zeros (N, 3) -> 384 floats per 128-pt block
  float* out2 = P.out + (size_t)NPTS * 4;
  if (tid < 96) {
    *(float4*)(out2 + (size_t)blockIdx.x * 384 + (size_t)tid * 4) =
        make_float4(0.f, 0.f, 0.f, 0.f);
  }
}

extern "C" void kernel_launch(void* const* d_in, const int* in_sizes, int n_in,
                              void* d_out, int out_size, void* d_ws, size_t ws_size,
                              hipStream_t stream) {
  (void)in_sizes; (void)n_in; (void)out_size; (void)ws_size;

  RepParams rp;
  rp.seg[0]  = { (const float*)d_in[1],    0,  63, 256, 8,    0 }; // w0 (pad K 63->64)
  rp.seg[1]  = { (const float*)d_in[3],    0, 256, 256, 8,   32 }; // w1
  rp.seg[2]  = { (const float*)d_in[5],    0, 256, 256, 8,  160 }; // w2
  rp.seg[3]  = { (const float*)d_in[7],    0, 256, 256, 8,  288 }; // w3
  rp.seg[4]  = { (const float*)d_in[9],    0, 256, 256, 8,  416 }; // w4
  rp.seg[5]  = { (const float*)d_in[11],  63, 256, 256, 8,  544 }; // w5 y-part (rows 63..318)
  rp.seg[6]  = { (const float*)d_in[11],   0,  63, 256, 8,  672 }; // w5 pos-part (rows 0..62)
  rp.seg[7]  = { (const float*)d_in[13],   0, 256, 256, 8,  704 }; // w6
  rp.seg[8]  = { (const float*)d_in[15],   0, 256, 256, 8,  832 }; // w7
  rp.seg[9]  = { (const float*)d_in[17],   0, 256, 256, 8,  960 }; // feat_w
  rp.seg[10] = { (const float*)d_in[21],   0, 256, 128, 4, 1088 }; // views_w feature-part
  rp.seg[11] = { (const float*)d_in[21], 256,  27, 128, 4, 1152 }; // views_w views-part
  rp.seg[12] = { (const float*)d_in[23],   0, 128,   3, 1, 1160 }; // rgb_w (pad 3->32 ch)
  rp.rep = (f16*)d_ws;
  repack_kernel<<<1168, 64, 0, stream>>>(rp);

  MainParams mp;
  mp.x = (const float*)d_in[0];
  for (int i = 0; i < 8; ++i) mp.b[i] = (const float*)d_in[2 + 2 * i];
  mp.feat_b  = (const float*)d_in[18];
  mp.alpha_w = (const float*)d_in[19];
  mp.alpha_b = (const float*)d_in[20];
  mp.views_b = (const float*)d_in[22];
  mp.rgb_b   = (const float*)d_in[24];
  mp.rep = (const f16*)d_ws;
  mp.out = (float*)d_out;
  nerf_main<<<2048, 256, 0, stream>>>(mp);
}

// Round 19
// 294.733 us; speedup vs baseline: 1.0658x; 1.0106x over previous
//
#include <hip/hip_runtime.h>
#include <cstdint>
#include <cstddef>

typedef _Float16 f16;
typedef _Float16 f16x8 __attribute__((ext_vector_type(8)));
typedef _Float16 f16x4 __attribute__((ext_vector_type(4)));
typedef float f32x16 __attribute__((ext_vector_type(16)));
typedef float f32x4 __attribute__((ext_vector_type(4)));

static constexpr int NPTS = 262144;

// Repacked weight offsets (in halfs). Each "tile" is 512 halfs = 64 lanes x 8.
// Fragment layout per tile (kt, ct): value = W[k][ch], k = kt*16 + (l>>5)*8 + j,
// ch = ct*32 + (l&31). Tiles ordered [segment][kt][ct], contiguous.
static constexpr int OFF_W0    = 0;        // 4 kt x 8 ct
static constexpr int OFF_W1    = 16384;    // 16 x 8
static constexpr int OFF_W2    = 81920;
static constexpr int OFF_W3    = 147456;
static constexpr int OFF_W4    = 212992;
static constexpr int OFF_W5    = 278528;   // w5b (16x8) then w5a (4x8), contiguous = 20 slices
static constexpr int OFF_W6    = 360448;
static constexpr int OFF_W7    = 425984;
static constexpr int OFF_FEAT  = 491520;
static constexpr int OFF_VIEWS = 557056;   // viewsA (16x4) then viewsB (2x4) = 18 slices of 2048
static constexpr int OFF_RGB   = 593920;   // 8 x 1

struct Seg { const float* src; int k0, rv, fo, ct, t0; };
struct RepParams { Seg seg[13]; f16* rep; };

__global__ void repack_kernel(RepParams P) {
  int tile = blockIdx.x;
  int s = 0;
  #pragma unroll
  for (int i = 1; i < 13; ++i)
    if (tile >= P.seg[i].t0) s = i;
  const Seg sg = P.seg[s];
  int local = tile - sg.t0;
  int kt = local / sg.ct;
  int ct = local - kt * sg.ct;
  int l = threadIdx.x;
  int ch = ct * 32 + (l & 31);
  int kbase = kt * 16 + ((l >> 5) << 3);
  f16x8 v;
  #pragma unroll
  for (int j = 0; j < 8; ++j) {
    int k = kbase + j;
    float val = 0.f;
    if (k < sg.rv && ch < sg.fo) val = sg.src[(size_t)(sg.k0 + k) * sg.fo + ch];
    v[j] = (f16)val;
  }
  *(f16x8*)(P.rep + (size_t)tile * 512 + (size_t)l * 8) = v;
}

struct MainParams {
  const float* x;
  const float* b[8];
  const float* feat_b;
  const float* alpha_w;
  const float* alpha_b;
  const float* views_b;
  const float* rgb_b;
  const f16* rep;
  float* out;
};

// Activation LDS: [pt<128][256ch] f16, 512 B rows, XOR swizzle.
__device__ __forceinline__ int act_off(int pt, int kbyte) {
  return pt * 512 + (kbyte ^ ((pt & 15) << 4));
}
// pos cache LDS: [pt<128][64ch] f16, 128 B rows, XOR swizzle.
__device__ __forceinline__ int pos_off(int pt, int kbyte) {
  return pt * 128 + (kbyte ^ ((pt & 7) << 4));
}

// LDS-only barrier for LAYER ENTRY: drains ds ops (lgkmcnt) then barriers,
// in ONE asm block (memory clobber -> no memory op crosses it; the rule-#18
// hazard concerns register-only MFMA, not present here). Unlike
// __syncthreads, this does NOT drain vmcnt -- the A[0]/A[1] weight
// prefetches issued just before stay in flight across the boundary.
// All pre-barrier producer->consumer deps here are LDS (epilogue writes ->
// B reads); globals are read-only until the final output store.
__device__ __forceinline__ void bar_l() {
  asm volatile("s_waitcnt lgkmcnt(0)\n\ts_barrier" ::: "memory");
}

// Packed f32x4 -> f16x4 epilogue convert (RELU optional): 4 fmax + 2
// v_cvt_pkrtz_f16_f32 instead of ~10 scalar cvt/pack ops. RTZ rounding is
// <= 1 ulp f16 off RNE; absmax headroom is ~5x. NOTE: the builtin returns
// __fp16x2, element-convert into our _Float16 vector (bit-identical).
template<bool RELU>
__device__ __forceinline__ f16x4 pack4(float v0, float v1, float v2, float v3) {
  if (RELU) {
    v0 = fmaxf(v0, 0.f); v1 = fmaxf(v1, 0.f);
    v2 = fmaxf(v2, 0.f); v3 = fmaxf(v3, 0.f);
  }
  auto lo = __builtin_amdgcn_cvt_pkrtz(v0, v1);
  auto hi = __builtin_amdgcn_cvt_pkrtz(v2, v3);
  f16x4 h;
  h[0] = (f16)lo[0]; h[1] = (f16)lo[1]; h[2] = (f16)hi[0]; h[3] = (f16)hi[1];
  return h;
}

// 256-out layer; block = 4 waves x 128 pts, 2 blocks/CU -> 2 waves/SIMD.
// Wave w: ch [64w, 64w+64) x all 128 pts; acc[c][p] = 128 f32 (AGPRs;
// 128 VGPR + 128 AGPR = full 256-reg budget at 2 waves/SIMD -- do NOT add
// register load: R13 spilled). SOFTWARE-PIPELINED: A depth-3 rotate (2 kt
// ahead), B depth-2 (1 kt ahead). setprio(1) around the MFMA cluster (T5).
// Tile shape is the box optimum: CH=64 puts LDS B-reads at ~75% of pipe
// (structural); CH=128 instead hits the 64 B/cyc L1 A-feed ceiling (R16).
template<int KTA, bool POSB, bool RELU>
__device__ __forceinline__ void layer_std(
    const f16* repL, const float* bias,
    f16* act, const f16* posb, int lane, int w)
{
  constexpr int NT = KTA + (POSB ? 4 : 0);
  const int l31 = lane & 31;
  const int ln5 = lane >> 5;
  const int chb = w * 64;

  f32x16 acc[2][4];
  #pragma unroll
  for (int c = 0; c < 2; ++c) {
    #pragma unroll
    for (int g = 0; g < 4; ++g) {
      f32x4 bv = *(const f32x4*)(bias + chb + c * 32 + g * 8 + (ln5 << 2));
      #pragma unroll
      for (int p = 0; p < 4; ++p) {
        #pragma unroll
        for (int q = 0; q < 4; ++q) acc[c][p][g * 4 + q] = bv[q];
      }
    }
  }

  auto lda = [&](int kt, int c) -> f16x8 {
    return *(const f16x8*)(repL + (size_t)(kt * 8 + 2 * w + c) * 512 + (size_t)lane * 8);
  };
  auto ldb = [&](int kt, int p) -> f16x8 {
    if (kt < KTA)
      return *(const f16x8*)((const char*)act + act_off(p * 32 + l31, (kt * 16 + ln5 * 8) * 2));
    else
      return *(const f16x8*)((const char*)posb + pos_off(p * 32 + l31, ((kt - KTA) * 16 + ln5 * 8) * 2));
  };

  f16x8 A[3][2], B[2][4];
  #pragma unroll
  for (int c = 0; c < 2; ++c) {
    A[0][c] = lda(0, c);
    A[1][c] = lda(1, c);   // NT >= 4 always
  }

  bar_l();  // prev epilogue writes (and prologue posb fill) visible;
            // A prefetches above stay in flight (no vmcnt drain)

  #pragma unroll
  for (int p = 0; p < 4; ++p) B[0][p] = ldb(0, p);

  #pragma unroll
  for (int kt = 0; kt < NT; ++kt) {
    if (kt + 2 < NT) {
      #pragma unroll
      for (int c = 0; c < 2; ++c) A[(kt + 2) % 3][c] = lda(kt + 2, c);
    }
    if (kt + 1 < NT) {
      #pragma unroll
      for (int p = 0; p < 4; ++p) B[(kt + 1) & 1][p] = ldb(kt + 1, p);
    }
    __builtin_amdgcn_s_setprio(1);
    #pragma unroll
    for (int c = 0; c < 2; ++c)
      #pragma unroll
      for (int p = 0; p < 4; ++p)
        acc[c][p] = __builtin_amdgcn_mfma_f32_32x32x16_f16(A[kt % 3][c], B[kt & 1][p], acc[c][p], 0, 0, 0);
    __builtin_amdgcn_s_setprio(0);
  }

  __syncthreads();  // all B reads done -> safe to overwrite act in place

  // Epilogue: C row = (r&3) + 8*(r>>2) + 4*(l>>5), col = l&31 (pt).
  #pragma unroll
  for (int c = 0; c < 2; ++c) {
    #pragma unroll
    for (int p = 0; p < 4; ++p) {
      int pt = p * 32 + l31;
      #pragma unroll
      for (int g = 0; g < 4; ++g) {
        f16x4 h = pack4<RELU>(acc[c][p][g * 4 + 0], acc[c][p][g * 4 + 1],
                              acc[c][p][g * 4 + 2], acc[c][p][g * 4 + 3]);
        int ch = chb + c * 32 + g * 8 + (ln5 << 2);
        *(f16x4*)((char*)act + act_off(pt, ch * 2)) = h;
      }
    }
  }
}

// Views layer: in = feature(256 from act) + views(27 gathered from x), out=128.
// Wave w -> ch [32w, 32w+32) x all 128 pts. Same pipelined K-loop.
__device__ __forceinline__ void layer_views(
    const f16* repL, const float* bias, f16* act,
    const float* xrow0, int lane, int w)
{
  const int l31 = lane & 31;
  const int ln5 = lane >> 5;
  const int chb = w * 32;

  f32x16 acc[4];
  #pragma unroll
  for (int g = 0; g < 4; ++g) {
    f32x4 bv = *(const f32x4*)(bias + chb + g * 8 + (ln5 << 2));
    #pragma unroll
    for (int p = 0; p < 4; ++p)
      #pragma unroll
      for (int q = 0; q < 4; ++q) acc[p][g * 4 + q] = bv[q];
  }

  // Views part first (gathered from x; no act dependency -> before sync).
  #pragma unroll
  for (int j = 0; j < 2; ++j) {
    f16x8 a = *(const f16x8*)(repL + (size_t)((16 + j) * 4 + w) * 512 + (size_t)lane * 8);
    #pragma unroll
    for (int p = 0; p < 4; ++p) {
      f16x8 vf;
      const float* row = xrow0 + (size_t)(p * 32 + l31) * 90;
      #pragma unroll
      for (int jj = 0; jj < 8; ++jj) {
        int c = j * 16 + ln5 * 8 + jj;
        vf[jj] = (f16)((c < 27) ? row[63 + c] : 0.f);
      }
      acc[p] = __builtin_amdgcn_mfma_f32_32x32x16_f16(a, vf, acc[p], 0, 0, 0);
    }
  }

  auto lda = [&](int kt) -> f16x8 {
    return *(const f16x8*)(repL + (size_t)(kt * 4 + w) * 512 + (size_t)lane * 8);
  };
  auto ldb = [&](int kt, int p) -> f16x8 {
    return *(const f16x8*)((const char*)act + act_off(p * 32 + l31, (kt * 16 + ln5 * 8) * 2));
  };

  f16x8 A[3], B[2][4];
  A[0] = lda(0);
  A[1] = lda(1);

  bar_l();

  #pragma unroll
  for (int p = 0; p < 4; ++p) B[0][p] = ldb(0, p);

  #pragma unroll
  for (int kt = 0; kt < 16; ++kt) {
    if (kt + 2 < 16) A[(kt + 2) % 3] = lda(kt + 2);
    if (kt + 1 < 16) {
      #pragma unroll
      for (int p = 0; p < 4; ++p) B[(kt + 1) & 1][p] = ldb(kt + 1, p);
    }
    __builtin_amdgcn_s_setprio(1);
    #pragma unroll
    for (int p = 0; p < 4; ++p)
      acc[p] = __builtin_amdgcn_mfma_f32_32x32x16_f16(A[kt % 3], B[kt & 1][p], acc[p], 0, 0, 0);
    __builtin_amdgcn_s_setprio(0);
  }

  __syncthreads();

  #pragma unroll
  for (int p = 0; p < 4; ++p) {
    int pt = p * 32 + l31;
    #pragma unroll
    for (int g = 0; g < 4; ++g) {
      f16x4 h = pack4<true>(acc[p][g * 4 + 0], acc[p][g * 4 + 1],
                            acc[p][g * 4 + 2], acc[p][g * 4 + 3]);
      int ch = chb + g * 8 + (ln5 << 2);
      *(f16x4*)((char*)act + act_off(pt, ch * 2)) = h;
    }
  }
}

// alpha = y . alpha_w + alpha_b. 2 threads per point (128 pts, 256 threads),
// intra-wave shfl reduce; result into alds (reused posb memory).
__device__ __forceinline__ void alpha_pass(const f16* act, const float* aw,
                                           const float* ab, float* alds, int tid)
{
  bar_l();
  int pt = tid >> 1;
  int h = tid & 1;
  float s = 0.f;
  #pragma unroll
  for (int i = 0; i < 16; ++i) {
    int k0 = h * 128 + i * 8;
    f16x8 v = *(const f16x8*)((const char*)act + act_off(pt, k0 * 2));
    f32x4 wa = *(const f32x4*)(aw + k0);
    f32x4 wb = *(const f32x4*)(aw + k0 + 4);
    #pragma unroll
    for (int q = 0; q < 4; ++q) {
      s += (float)v[q] * wa[q];
      s += (float)v[q + 4] * wb[q];
    }
  }
  s += __shfl_xor(s, 1);
  if (h == 0) alds[pt] = s + ab[0];
}

// rgb (128 -> 3 via one padded 32-ch MFMA tile per wave): pt-tile = w.
// A fully preloaded (8 frags), B depth-2 pipelined.
__device__ __forceinline__ void layer_rgb_store(
    const f16* repL, f16* act, const float* alds,
    const float* rgb_b, float* out, int pt0, int lane, int w)
{
  f16x8 A[8];
  #pragma unroll
  for (int kt = 0; kt < 8; ++kt)
    A[kt] = *(const f16x8*)(repL + (size_t)kt * 512 + (size_t)lane * 8);

  bar_l();

  auto ldb = [&](int kt) -> f16x8 {
    return *(const f16x8*)((const char*)act + act_off(w * 32 + (lane & 31), (kt * 16 + (lane >> 5) * 8) * 2));
  };

  f32x16 acc = {};
  f16x8 B[2];
  B[0] = ldb(0);
  #pragma unroll
  for (int kt = 0; kt < 8; ++kt) {
    if (kt + 1 < 8) B[(kt + 1) & 1] = ldb(kt + 1);
    acc = __builtin_amdgcn_mfma_f32_32x32x16_f16(A[kt], B[kt & 1], acc, 0, 0, 0);
  }

  if (lane < 32) {
    int pt = w * 32 + lane;
    float4 o;
    o.x = acc[0] + rgb_b[0];
    o.y = acc[1] + rgb_b[1];
    o.z = acc[2] + rgb_b[2];
    o.w = alds[pt];
    *(float4*)(out + (size_t)(pt0 + pt) * 4) = o;
  }
}

__global__ __launch_bounds__(256, 2) void nerf_main(MainParams P) {
  __shared__ __align__(16) f16 act[32768];   // 64 KB: [128 pt][256 k], swizzled
  __shared__ __align__(16) f16 posb[8192];   // 16 KB: [128 pt][64 k] pos cache

  const int tid = threadIdx.x;
  const int lane = tid & 63;
  const int w = tid >> 6;                // 4 waves
  const int pt0 = blockIdx.x * 128;
  const float* xrow0 = P.x + (size_t)pt0 * 90;

  // Prologue: gather pos (63 ch, pad to 64) into posb ONCE, B-frag layout.
  // 256 threads: pt = tid&127, col-half q = tid>>7 (32 ch each).
  // Rows are 8-byte aligned (90 floats = 360 B stride) -> float2 loads.
  {
    int pt = tid & 127;
    int q = tid >> 7;
    const float* rowq = xrow0 + (size_t)pt * 90 + q * 32;
    #pragma unroll
    for (int h = 0; h < 4; ++h) {
      f16x8 v;
      #pragma unroll
      for (int m = 0; m < 4; ++m) {
        float2 f = *(const float2*)(rowq + h * 8 + m * 2);
        v[m * 2]     = (f16)f.x;
        v[m * 2 + 1] = (f16)f.y;
      }
      if (q == 1 && h == 3) v[7] = (f16)0.f;   // pad k=63 -> 0
      *(f16x8*)((char*)posb + pos_off(pt, (q * 32 + h * 8) * 2)) = v;
    }
  }

  layer_std<0, true, true>(P.rep + OFF_W0, P.b[0], act, posb, lane, w);
  layer_std<16, false, true>(P.rep + OFF_W1, P.b[1], act, posb, lane, w);
  layer_std<16, false, true>(P.rep + OFF_W2, P.b[2], act, posb, lane, w);
  layer_std<16, false, true>(P.rep + OFF_W3, P.b[3], act, posb, lane, w);
  layer_std<16, false, true>(P.rep + OFF_W4, P.b[4], act, posb, lane, w);
  layer_std<16, true, true>(P.rep + OFF_W5, P.b[5], act, posb, lane, w);
  layer_std<16, false, true>(P.rep + OFF_W6, P.b[6], act, posb, lane, w);
  layer_std<16, false, true>(P.rep + OFF_W7, P.b[7], act, posb, lane, w);

  // posb is dead after L5 -> reuse as alpha scratch.
  float* alds = (float*)posb;
  alpha_pass(act, P.alpha_w, P.alpha_b, alds, tid);

  layer_std<16, false, false>(P.rep + OFF_FEAT, P.feat_b, act, posb, lane, w);

  layer_views(P.rep + OFF_VIEWS, P.views_b, act, xrow0, lane, w);

  layer_rgb_store(P.rep + OFF_RGB, act, alds, P.rgb_b, P.out, pt0, lane, w);

  // Second tuple output: zeros (N, 3) -> 384 floats per 128-pt block
  float* out2 = P.out + (size_t)NPTS * 4;
  if (tid < 96) {
    *(float4*)(out2 + (size_t)blockIdx.x * 384 + (size_t)tid * 4) =
        make_float4(0.f, 0.f, 0.f, 0.f);
  }
}

extern "C" void kernel_launch(void* const* d_in, const int* in_sizes, int n_in,
                              void* d_out, int out_size, void* d_ws, size_t ws_size,
                              hipStream_t stream) {
  (void)in_sizes; (void)n_in; (void)out_size; (void)ws_size;

  RepParams rp;
  rp.seg[0]  = { (const float*)d_in[1],    0,  63, 256, 8,    0 }; // w0 (pad K 63->64)
  rp.seg[1]  = { (const float*)d_in[3],    0, 256, 256, 8,   32 }; // w1
  rp.seg[2]  = { (const float*)d_in[5],    0, 256, 256, 8,  160 }; // w2
  rp.seg[3]  = { (const float*)d_in[7],    0, 256, 256, 8,  288 }; // w3
  rp.seg[4]  = { (const float*)d_in[9],    0, 256, 256, 8,  416 }; // w4
  rp.seg[5]  = { (const float*)d_in[11],  63, 256, 256, 8,  544 }; // w5 y-part (rows 63..318)
  rp.seg[6]  = { (const float*)d_in[11],   0,  63, 256, 8,  672 }; // w5 pos-part (rows 0..62)
  rp.seg[7]  = { (const float*)d_in[13],   0, 256, 256, 8,  704 }; // w6
  rp.seg[8]  = { (const float*)d_in[15],   0, 256, 256, 8,  832 }; // w7
  rp.seg[9]  = { (const float*)d_in[17],   0, 256, 256, 8,  960 }; // feat_w
  rp.seg[10] = { (const float*)d_in[21],   0, 256, 128, 4, 1088 }; // views_w feature-part
  rp.seg[11] = { (const float*)d_in[21], 256,  27, 128, 4, 1152 }; // views_w views-part
  rp.seg[12] = { (const float*)d_in[23],   0, 128,   3, 1, 1160 }; // rgb_w (pad 3->32 ch)
  rp.rep = (f16*)d_ws;
  repack_kernel<<<1168, 64, 0, stream>>>(rp);

  MainParams mp;
  mp.x = (const float*)d_in[0];
  for (int i = 0; i < 8; ++i) mp.b[i] = (const float*)d_in[2 + 2 * i];
  mp.feat_b  = (const float*)d_in[18];
  mp.alpha_w = (const float*)d_in[19];
  mp.alpha_b = (const float*)d_in[20];
  mp.views_b = (const float*)d_in[22];
  mp.rgb_b   = (const float*)d_in[24];
  mp.rep = (const f16*)d_ws;
  mp.out = (float*)d_out;
  nerf_main<<<2048, 256, 0, stream>>>(mp);
}